// Round 4
// baseline (666.664 us; speedup 1.0000x reference)
//
#include <hip/hip_runtime.h>
#include <hip/hip_bf16.h>

// Problem constants (from reference)
#define N_CLASSES  10
#define N_TREES    4000
#define DEPTH      6
#define N_INTERNAL 63
#define N_FEATURES 128
#define BATCH      32768
#define LR         0.1f

// Kernel config
#define BLOCK      256
#define SAMPLES_PB 32
#define J_CHUNKS   8                      // tid>>5
#define CHUNK      5                      // trees per thread per tile
#define T_TILE     40                     // J_CHUNKS * CHUNK
#define TSPLIT     2                      // tree split across blockIdx.y
#define TREES_PB   (N_TREES / TSPLIT)     // 2000
#define N_TILES    (TREES_PB / T_TILE)    // 50

// ws layout: per tree 128 dwords: [0..63] = feat (int), [64..127] = thr (f32 bits).
// Contiguous per tree -> tile staging is a straight 20 KB block copy.
__global__ void pack_nodes_kernel(const int* __restrict__ features,
                                  const float* __restrict__ thresholds,
                                  int* __restrict__ packed) {
    int i = blockIdx.x * blockDim.x + threadIdx.x;
    if (i < N_TREES * N_INTERNAL) {
        int t = i / N_INTERNAL;
        int n = i - t * N_INTERNAL;
        packed[t * 128 + n]      = features[i];
        packed[t * 128 + 64 + n] = __float_as_int(thresholds[i]);
    }
}

// out[s][k] = init_out[k]; eval blocks (2 per sample) atomicAdd their partials.
__global__ void out_init_kernel(const float* __restrict__ init_out,
                                float* __restrict__ out) {
    int i = blockIdx.x * blockDim.x + threadIdx.x;
    if (i < BATCH * N_CLASSES) {
        int s = i / N_CLASSES;
        out[i] = init_out[i - s * N_CLASSES];
    }
}

__global__ __launch_bounds__(BLOCK, 3) void gbt_eval_lds(
    const float* __restrict__ x,
    const int*   __restrict__ packed,      // [N_TREES][128] dwords
    const float* __restrict__ leaf_values, // [N_TREES][64]
    float*       __restrict__ out)
{
    __shared__ float xs[N_FEATURES * SAMPLES_PB];   // 16 KB, transposed
    __shared__ int   nds[T_TILE * 128];             // 20 KB node tile
    __shared__ float lvs[T_TILE * 64];              // 10 KB leaf tile
    __shared__ float sums[SAMPLES_PB * N_CLASSES];  // 1.25 KB

    const int tid = threadIdx.x;
    const int sample0  = blockIdx.x * SAMPLES_PB;
    const int treeBase = blockIdx.y * TREES_PB;

    // Stage x rows (transposed: bank = sample % 32 -> hot-loop reads conflict-free)
    {
        const float4* xg = (const float4*)(x + (size_t)sample0 * N_FEATURES);
        for (int e = tid; e < SAMPLES_PB * (N_FEATURES / 4); e += BLOCK) {
            int s = e >> 5, f4 = e & 31;
            float4 v = xg[e];
            int f = f4 << 2;
            xs[(f + 0) * SAMPLES_PB + s] = v.x;
            xs[(f + 1) * SAMPLES_PB + s] = v.y;
            xs[(f + 2) * SAMPLES_PB + s] = v.z;
            xs[(f + 3) * SAMPLES_PB + s] = v.w;
        }
    }
    for (int i = tid; i < SAMPLES_PB * N_CLASSES; i += BLOCK) sums[i] = 0.f;

    // Tile staging: 40 trees = 5120 node dwords (1280 int4) + 2560 leaf floats
    // (1280 float2); exactly 5 vector elements per thread each. Register
    // double-buffer: prefetch tile t+1 during compute of tile t.
    int4   nreg[5];
    float2 lreg[5];
    const int4*   gn0 = (const int4*)(packed + (size_t)treeBase * 128);
    const float2* gl0 = (const float2*)(leaf_values + (size_t)treeBase * 64);

    #pragma unroll
    for (int k = 0; k < 5; ++k) nreg[k] = gn0[k * BLOCK + tid];
    #pragma unroll
    for (int k = 0; k < 5; ++k) lreg[k] = gl0[k * BLOCK + tid];
    {
        int4* sn = (int4*)nds; float2* sl = (float2*)lvs;
        #pragma unroll
        for (int k = 0; k < 5; ++k) sn[k * BLOCK + tid] = nreg[k];
        #pragma unroll
        for (int k = 0; k < 5; ++k) sl[k * BLOCK + tid] = lreg[k];
    }
    __syncthreads();

    // Lanes 0-31 / 32-63 = samples x two tree-chunks (2-way LDS alias = free).
    const int sLocal = tid & (SAMPLES_PB - 1);
    const int j      = tid >> 5;               // 0..7
    const int cbase  = (j & 1) * 5;            // class base: (j*5+u)%10 = cbase+u
    const int*   nb = nds + j * CHUNK * 128;
    const float* lb = lvs + j * CHUNK * 64;

    float acc[CHUNK] = {0.f, 0.f, 0.f, 0.f, 0.f};

    for (int tile = 0; tile < N_TILES; ++tile) {
        if (tile + 1 < N_TILES) {   // prefetch next tile into registers
            #pragma unroll
            for (int k = 0; k < 5; ++k) nreg[k] = gn0[(tile + 1) * 1280 + k * BLOCK + tid];
            #pragma unroll
            for (int k = 0; k < 5; ++k) lreg[k] = gl0[(tile + 1) * 1280 + k * BLOCK + tid];
        }

        int o[CHUNK];
        #pragma unroll
        for (int u = 0; u < CHUNK; ++u) o[u] = 0;

        #pragma unroll
        for (int d = 0; d < DEPTH; ++d) {
            int f[CHUNK]; float th[CHUNK];
            #pragma unroll
            for (int u = 0; u < CHUNK; ++u) {
                const int* p = nb + u * 128 + o[u];
                f[u]  = p[0];                       // ds_read2_b32 (+0, +64 dw)
                th[u] = __int_as_float(p[64]);      // banks = idx%32: conflict-free
            }
            float xv[CHUNK];
            #pragma unroll
            for (int u = 0; u < CHUNK; ++u)
                xv[u] = xs[f[u] * SAMPLES_PB + sLocal];
            #pragma unroll
            for (int u = 0; u < CHUNK; ++u)
                o[u] = 2 * o[u] + 1 + (xv[u] > th[u] ? 1 : 0);
        }
        #pragma unroll
        for (int u = 0; u < CHUNK; ++u)
            acc[u] += lb[u * 64 + o[u] - N_INTERNAL];

        if (tile + 1 < N_TILES) {
            __syncthreads();        // all waves done reading current tile
            int4* sn = (int4*)nds; float2* sl = (float2*)lvs;
            #pragma unroll
            for (int k = 0; k < 5; ++k) sn[k * BLOCK + tid] = nreg[k];
            #pragma unroll
            for (int k = 0; k < 5; ++k) sl[k * BLOCK + tid] = lreg[k];
            __syncthreads();        // new tile visible to all
        }
    }

    #pragma unroll
    for (int u = 0; u < CHUNK; ++u)
        atomicAdd(&sums[sLocal * N_CLASSES + cbase + u], acc[u]);
    __syncthreads();

    for (int e = tid; e < SAMPLES_PB * N_CLASSES; e += BLOCK) {
        int s = e / N_CLASSES, k = e - s * N_CLASSES;
        atomicAdd(&out[(size_t)(sample0 + s) * N_CLASSES + k], LR * sums[e]);
    }
}

// Fallback (ws too small): R3-style direct-global gather.
__global__ __launch_bounds__(BLOCK, 8) void gbt_eval_global(
    const float* __restrict__ x,
    const int*   __restrict__ features,
    const float* __restrict__ thresholds,
    const float* __restrict__ leaf_values,
    float*       __restrict__ out)
{
    __shared__ float xs[N_FEATURES * SAMPLES_PB];
    __shared__ float sums[SAMPLES_PB * N_CLASSES];
    const int tid = threadIdx.x;
    const int sample0 = blockIdx.x * SAMPLES_PB;
    {
        const float4* xg = (const float4*)(x + (size_t)sample0 * N_FEATURES);
        for (int e = tid; e < SAMPLES_PB * (N_FEATURES / 4); e += BLOCK) {
            int s = e >> 5, f4 = e & 31;
            float4 v = xg[e];
            int f = f4 << 2;
            xs[(f + 0) * SAMPLES_PB + s] = v.x;
            xs[(f + 1) * SAMPLES_PB + s] = v.y;
            xs[(f + 2) * SAMPLES_PB + s] = v.z;
            xs[(f + 3) * SAMPLES_PB + s] = v.w;
        }
    }
    for (int i = tid; i < SAMPLES_PB * N_CLASSES; i += BLOCK) sums[i] = 0.f;
    __syncthreads();
    const int sLocal = tid & (SAMPLES_PB - 1);
    const int j = tid >> 5;
    const int t0 = (blockIdx.y * J_CHUNKS + j) * (N_TREES / (J_CHUNKS * TSPLIT));
    float acc[N_CLASSES];
    #pragma unroll
    for (int k = 0; k < N_CLASSES; ++k) acc[k] = 0.f;
    for (int i = 0; i < N_TREES / (J_CHUNKS * TSPLIT); i += N_CLASSES) {
        const int tt = t0 + i;
        int idx[N_CLASSES];
        #pragma unroll
        for (int u = 0; u < N_CLASSES; ++u) idx[u] = 0;
        #pragma unroll
        for (int d = 0; d < DEPTH; ++d) {
            #pragma unroll
            for (int u = 0; u < N_CLASSES; ++u) {
                int base = (tt + u) * N_INTERNAL + idx[u];
                float xv = xs[features[base] * SAMPLES_PB + sLocal];
                idx[u] = 2 * idx[u] + 1 + (xv > thresholds[base] ? 1 : 0);
            }
        }
        #pragma unroll
        for (int u = 0; u < N_CLASSES; ++u)
            acc[u] += leaf_values[(size_t)(tt + u) * 64 + idx[u] - N_INTERNAL];
    }
    #pragma unroll
    for (int k = 0; k < N_CLASSES; ++k)
        atomicAdd(&sums[sLocal * N_CLASSES + k], acc[k]);
    __syncthreads();
    for (int e = tid; e < SAMPLES_PB * N_CLASSES; e += BLOCK) {
        int s = e / N_CLASSES, k = e - s * N_CLASSES;
        atomicAdd(&out[(size_t)(sample0 + s) * N_CLASSES + k], LR * sums[e]);
    }
}

extern "C" void kernel_launch(void* const* d_in, const int* in_sizes, int n_in,
                              void* d_out, int out_size, void* d_ws, size_t ws_size,
                              hipStream_t stream) {
    const float* x          = (const float*)d_in[0];
    const int*   features   = (const int*)d_in[1];
    const float* thresholds = (const float*)d_in[2];
    const float* leafvals   = (const float*)d_in[3];
    const float* init_out   = (const float*)d_in[4];
    float*       out        = (float*)d_out;

    const size_t packed_bytes = (size_t)N_TREES * 128 * sizeof(int);  // 2 MB
    dim3 grid(BATCH / SAMPLES_PB, TSPLIT);                            // 1024 x 2

    {
        int n = BATCH * N_CLASSES;
        out_init_kernel<<<(n + 255) / 256, 256, 0, stream>>>(init_out, out);
    }

    if (ws_size >= packed_bytes) {
        int* packed = (int*)d_ws;
        int n = N_TREES * N_INTERNAL;
        pack_nodes_kernel<<<(n + 255) / 256, 256, 0, stream>>>(features, thresholds, packed);
        gbt_eval_lds<<<grid, BLOCK, 0, stream>>>(x, packed, leafvals, out);
    } else {
        gbt_eval_global<<<grid, BLOCK, 0, stream>>>(x, features, thresholds, leafvals, out);
    }
}

// Round 5
// 335.214 us; speedup vs baseline: 1.9888x; 1.9888x over previous
//
#include <hip/hip_runtime.h>
#include <stdint.h>

// Problem constants (from reference)
#define N_CLASSES  10
#define N_TREES    4000
#define DEPTH      6
#define N_INTERNAL 63
#define N_FEATURES 128
#define BATCH      32768
#define LR         0.1f

// Kernel config
#define BLOCK       256
#define SAMPLES_PB  32
#define TSPLIT      2                       // tree split across blockIdx.y
#define SLOTS_PB    (N_TREES / TSPLIT)      // 2000 class-grouped slots per block
#define T_TILE      16                      // trees per LDS tile (8 KB nodes)
#define N_TILES     (SLOTS_PB / T_TILE)     // 125
#define TILES_PER_CLASS 25                  // 400 trees/class / 16
#define NODE_DW     128                     // dwords per tree in packed nodes
#define SUMS_STRIDE 11                      // 11 coprime to 32: conflict-free-ish

// ws layout: [0, 2.048MB) nodes by slot ([feat x64][thr x64] dwords per tree);
//            [2.048MB, 3.072MB) leaves by slot (64 floats per tree).
// Slot permutation groups trees by class: slot = (t%10)*400 + t/10.
#define WS_NODES_BYTES  ((size_t)N_TREES * NODE_DW * 4)
#define WS_LEAVES_BYTES ((size_t)N_TREES * 64 * 4)

__global__ void pack_kernel(const int* __restrict__ features,
                            const float* __restrict__ thresholds,
                            const float* __restrict__ leaves,
                            int* __restrict__ pn, float* __restrict__ pl) {
    int i = blockIdx.x * blockDim.x + threadIdx.x;   // over N_TREES*64
    int t = i >> 6, n = i & 63;
    if (t < N_TREES) {
        int slot = (t % N_CLASSES) * (N_TREES / N_CLASSES) + (t / N_CLASSES);
        if (n < N_INTERNAL) {
            pn[slot * NODE_DW + n]      = features[t * N_INTERNAL + n];
            pn[slot * NODE_DW + 64 + n] = __float_as_int(thresholds[t * N_INTERNAL + n]);
        }
        pl[slot * 64 + n] = leaves[t * 64 + n];
    }
}

__global__ void out_init_kernel(const float* __restrict__ init_out,
                                float* __restrict__ out) {
    int i = blockIdx.x * blockDim.x + threadIdx.x;
    if (i < BATCH * N_CLASSES) {
        int s = i / N_CLASSES;
        out[i] = init_out[i - s * N_CLASSES];
    }
}

// CK-style addrspace casts for global_load_lds (only these forms compile).
__device__ __forceinline__ void load_lds_16(const void* g, void* l) {
    const auto* g1 = reinterpret_cast<const __attribute__((address_space(1))) uint32_t*>(
        reinterpret_cast<uintptr_t>(g));
    auto* l3 = reinterpret_cast<__attribute__((address_space(3))) uint32_t*>(
        reinterpret_cast<uintptr_t>(l));
    __builtin_amdgcn_global_load_lds(g1, l3, 16, 0, 0);
}

__global__ __launch_bounds__(BLOCK, 4) void gbt_eval(
    const float* __restrict__ x,
    const int*   __restrict__ pnodes,   // [N_TREES][128] dw, class-grouped slots
    const float* __restrict__ pleaves,  // [N_TREES][64], class-grouped slots
    float*       __restrict__ out)      // [BATCH][10], pre-init to init_out
{
    __shared__ float xs[N_FEATURES * SAMPLES_PB];       // 16 KB, transposed
    __shared__ int   nbuf[2][T_TILE * NODE_DW];         // 2 x 8 KB node tiles
    __shared__ float sums[SAMPLES_PB * SUMS_STRIDE];    // 1.4 KB

    const int tid = threadIdx.x;
    const int sample0 = blockIdx.x * SAMPLES_PB;
    const int slot0   = blockIdx.y * SLOTS_PB;
    const int cls0    = blockIdx.y * (N_CLASSES / TSPLIT);  // 5 classes per block

    // Stage x transposed: xs[f*32 + s]; hot-loop bank = s%32, conflict-free.
    {
        const float4* xg = (const float4*)(x + (size_t)sample0 * N_FEATURES);
        for (int e = tid; e < SAMPLES_PB * (N_FEATURES / 4); e += BLOCK) {
            int s = e >> 5, f4 = e & 31;
            float4 v = xg[e];
            int f = f4 << 2;
            xs[(f + 0) * SAMPLES_PB + s] = v.x;
            xs[(f + 1) * SAMPLES_PB + s] = v.y;
            xs[(f + 2) * SAMPLES_PB + s] = v.z;
            xs[(f + 3) * SAMPLES_PB + s] = v.w;
        }
    }
    for (int i = tid; i < SAMPLES_PB * SUMS_STRIDE; i += BLOCK) sums[i] = 0.f;

    const int lane = tid & 63;
    const int wv   = tid >> 6;          // wave id 0..3

    // Stage one 8 KB node tile: 8 chunks of 1 KB; wave wv DMAs chunks 2wv, 2wv+1.
    // LDS dest is wave-uniform; HW scatters lane i to base + i*16.
    auto stage = [&](int tile, int b) {
        const char* g = (const char*)(pnodes + (size_t)(slot0 + tile * T_TILE) * NODE_DW);
        char* lbase = (char*)&nbuf[b][0];
        #pragma unroll
        for (int q = 0; q < 2; ++q) {
            int k = wv * 2 + q;
            load_lds_16(g + k * 1024 + lane * 16, lbase + k * 1024);
        }
    };

    stage(0, 0);
    __syncthreads();   // drains vmcnt(0): tile 0 + xs visible

    const int sLocal = tid & (SAMPLES_PB - 1);
    const int j      = tid >> 5;        // 0..7 half-wave chunks; trees 2j, 2j+1

    int cur = 0;
    for (int c5 = 0; c5 < N_CLASSES / TSPLIT; ++c5) {
        float acc = 0.f;                // single class per tile (class-grouped slots)
        for (int t25 = 0; t25 < TILES_PER_CLASS; ++t25) {
            const int tile = c5 * TILES_PER_CLASS + t25;
            if (tile + 1 < N_TILES) stage(tile + 1, cur ^ 1);

            const int* nb = &nbuf[cur][j * 2 * NODE_DW];
            int o0 = 0, o1 = 0;
            #pragma unroll
            for (int d = 0; d < DEPTH; ++d) {
                int   f0 = nb[o0];                              // ds_read2_b32
                float h0 = __int_as_float(nb[o0 + 64]);         // banks = o%32: clean
                int   f1 = nb[NODE_DW + o1];
                float h1 = __int_as_float(nb[NODE_DW + o1 + 64]);
                float x0 = xs[f0 * SAMPLES_PB + sLocal];
                float x1 = xs[f1 * SAMPLES_PB + sLocal];
                o0 = 2 * o0 + 1 + (x0 > h0 ? 1 : 0);
                o1 = 2 * o1 + 1 + (x1 > h1 ? 1 : 0);
            }
            const size_t slotA = (size_t)(slot0 + tile * T_TILE + j * 2);
            acc += pleaves[slotA * 64       + (o0 - N_INTERNAL)];   // L2-resident
            acc += pleaves[(slotA + 1) * 64 + (o1 - N_INTERNAL)];

            __syncthreads();   // all reads of nbuf[cur] done; prefetch (issued
            cur ^= 1;          // ~2000 cyc ago) drained without stall
        }
        atomicAdd(&sums[sLocal * SUMS_STRIDE + cls0 + c5], acc);
    }
    __syncthreads();

    for (int e = tid; e < SAMPLES_PB * N_CLASSES; e += BLOCK) {
        int s = e / N_CLASSES, k = e - s * N_CLASSES;
        atomicAdd(&out[(size_t)(sample0 + s) * N_CLASSES + k],
                  LR * sums[s * SUMS_STRIDE + k]);
    }
}

// Fallback (ws too small): R3-style direct-global gather (478 us, passed).
__global__ __launch_bounds__(BLOCK, 8) void gbt_eval_global(
    const float* __restrict__ x,
    const int*   __restrict__ features,
    const float* __restrict__ thresholds,
    const float* __restrict__ leaf_values,
    float*       __restrict__ out)
{
    __shared__ float xs[N_FEATURES * SAMPLES_PB];
    __shared__ float sums[SAMPLES_PB * N_CLASSES];
    const int tid = threadIdx.x;
    const int sample0 = blockIdx.x * SAMPLES_PB;
    {
        const float4* xg = (const float4*)(x + (size_t)sample0 * N_FEATURES);
        for (int e = tid; e < SAMPLES_PB * (N_FEATURES / 4); e += BLOCK) {
            int s = e >> 5, f4 = e & 31;
            float4 v = xg[e];
            int f = f4 << 2;
            xs[(f + 0) * SAMPLES_PB + s] = v.x;
            xs[(f + 1) * SAMPLES_PB + s] = v.y;
            xs[(f + 2) * SAMPLES_PB + s] = v.z;
            xs[(f + 3) * SAMPLES_PB + s] = v.w;
        }
    }
    for (int i = tid; i < SAMPLES_PB * N_CLASSES; i += BLOCK) sums[i] = 0.f;
    __syncthreads();
    const int sLocal = tid & (SAMPLES_PB - 1);
    const int j = tid >> 5;
    const int TPT = N_TREES / (8 * TSPLIT);
    const int t0 = (blockIdx.y * 8 + j) * TPT;
    float acc[N_CLASSES];
    #pragma unroll
    for (int k = 0; k < N_CLASSES; ++k) acc[k] = 0.f;
    for (int i = 0; i < TPT; i += N_CLASSES) {
        const int tt = t0 + i;
        int idx[N_CLASSES];
        #pragma unroll
        for (int u = 0; u < N_CLASSES; ++u) idx[u] = 0;
        #pragma unroll
        for (int d = 0; d < DEPTH; ++d) {
            #pragma unroll
            for (int u = 0; u < N_CLASSES; ++u) {
                int base = (tt + u) * N_INTERNAL + idx[u];
                float xv = xs[features[base] * SAMPLES_PB + sLocal];
                idx[u] = 2 * idx[u] + 1 + (xv > thresholds[base] ? 1 : 0);
            }
        }
        #pragma unroll
        for (int u = 0; u < N_CLASSES; ++u)
            acc[u] += leaf_values[(size_t)(tt + u) * 64 + idx[u] - N_INTERNAL];
    }
    #pragma unroll
    for (int k = 0; k < N_CLASSES; ++k)
        atomicAdd(&sums[sLocal * N_CLASSES + k], acc[k]);
    __syncthreads();
    for (int e = tid; e < SAMPLES_PB * N_CLASSES; e += BLOCK) {
        int s = e / N_CLASSES, k = e - s * N_CLASSES;
        atomicAdd(&out[(size_t)(sample0 + s) * N_CLASSES + k], LR * sums[e]);
    }
}

extern "C" void kernel_launch(void* const* d_in, const int* in_sizes, int n_in,
                              void* d_out, int out_size, void* d_ws, size_t ws_size,
                              hipStream_t stream) {
    const float* x          = (const float*)d_in[0];
    const int*   features   = (const int*)d_in[1];
    const float* thresholds = (const float*)d_in[2];
    const float* leafvals   = (const float*)d_in[3];
    const float* init_out   = (const float*)d_in[4];
    float*       out        = (float*)d_out;

    {
        int n = BATCH * N_CLASSES;
        out_init_kernel<<<(n + 255) / 256, 256, 0, stream>>>(init_out, out);
    }

    dim3 grid(BATCH / SAMPLES_PB, TSPLIT);  // 1024 x 2

    if (ws_size >= WS_NODES_BYTES + WS_LEAVES_BYTES) {
        int*   pn = (int*)d_ws;
        float* pl = (float*)((char*)d_ws + WS_NODES_BYTES);
        int n = N_TREES * 64;
        pack_kernel<<<(n + 255) / 256, 256, 0, stream>>>(features, thresholds,
                                                         leafvals, pn, pl);
        gbt_eval<<<grid, BLOCK, 0, stream>>>(x, pn, pl, out);
    } else {
        gbt_eval_global<<<grid, BLOCK, 0, stream>>>(x, features, thresholds,
                                                    leafvals, out);
    }
}